// Round 1
// baseline (242.630 us; speedup 1.0000x reference)
//
#include <hip/hip_runtime.h>

// SpatialTransformer3D: trilinear resample of (B=4, H=128, W=128, D=128, C=2) f32
// volume through per-batch 3x4 affine. Output (4,128,128,128,2) f32.
//
// Reference semantics replicated exactly:
//   n = i*r1*r2 + j*r2 + k  (r0=r1=r2=128)
//   x_norm = -1 + j*2/127 ; y_norm = -1 + i*2/127 ; z_norm = -1 + k*2/127
//   sg = P(3x4) @ [x,y,z,1] ;  x = (sg0+1)*64, y = (sg1+1)*64, z = (sg2+1)*64
//   x0 = clip(trunc(x),0,127), x1 = clip(trunc(x)+1,0,127)  (trunc toward zero)
//   weights from CLIPPED int coords: (x1f-x) for x0-taps, (x-x0f) for x1-taps
//   gather idx = z*16384 + y*128 + x  into per-batch flat volume, addr = idx*2+c

#define NB 4
#define DIM 128
#define NPTS (DIM * DIM * DIM)        // 2^21 points per batch
#define LOG_NPTS 21

__global__ __launch_bounds__(256) void st3d_kernel(
    const float* __restrict__ images,      // (B, H, W, D, C) = (4, 128,128,128, 2)
    const float* __restrict__ params,      // (B, 12)
    float* __restrict__ out)               // (B, 128,128,128, 2)
{
    const int tid = blockIdx.x * 256 + threadIdx.x;       // 0 .. B*2^21-1
    const int b   = tid >> LOG_NPTS;                      // uniform per block
    const int n   = tid & (NPTS - 1);
    const int i   = n >> 14;          // r0 index  -> y_norm
    const int j   = (n >> 7) & 127;   // r1 index  -> x_norm
    const int k   = n & 127;          // r2 index  -> z_norm

    const float* p = params + b * 12;

    const float step = 2.0f / 127.0f;
    const float xn = fmaf((float)j, step, -1.0f);
    const float yn = fmaf((float)i, step, -1.0f);
    const float zn = fmaf((float)k, step, -1.0f);

    const float sg0 = p[0] * xn + p[1] * yn + p[2]  * zn + p[3];
    const float sg1 = p[4] * xn + p[5] * yn + p[6]  * zn + p[7];
    const float sg2 = p[8] * xn + p[9] * yn + p[10] * zn + p[11];

    const float x = (sg0 + 1.0f) * 64.0f;   // 0.5 * (sg+1) * 128
    const float y = (sg1 + 1.0f) * 64.0f;
    const float z = (sg2 + 1.0f) * 64.0f;

    const int xi = (int)x, yi = (int)y, zi = (int)z;   // trunc toward zero, like astype(int32)
    const int x0 = min(max(xi, 0), 127), x1 = min(max(xi + 1, 0), 127);
    const int y0 = min(max(yi, 0), 127), y1 = min(max(yi + 1, 0), 127);
    const int z0 = min(max(zi, 0), 127), z1 = min(max(zi + 1, 0), 127);

    // weights from clipped coords (replicates edge behavior exactly)
    const float wx0 = (float)x1 - x, wx1 = x - (float)x0;
    const float wy0 = (float)y1 - y, wy1 = y - (float)y0;
    const float wz0 = (float)z1 - z, wz1 = z - (float)z0;

    const float2* __restrict__ vol =
        (const float2*)(images) + (size_t)b * NPTS;     // per-batch volume, float2 = both channels

    const float2 t000 = vol[(z0 << 14) + (y0 << 7) + x0];
    const float2 t100 = vol[(z1 << 14) + (y0 << 7) + x0];
    const float2 t010 = vol[(z0 << 14) + (y1 << 7) + x0];
    const float2 t110 = vol[(z1 << 14) + (y1 << 7) + x0];
    const float2 t001 = vol[(z0 << 14) + (y0 << 7) + x1];
    const float2 t101 = vol[(z1 << 14) + (y0 << 7) + x1];
    const float2 t011 = vol[(z0 << 14) + (y1 << 7) + x1];
    const float2 t111 = vol[(z1 << 14) + (y1 << 7) + x1];

    const float w000 = wx0 * wy0 * wz0;
    const float w100 = wx0 * wy0 * wz1;
    const float w010 = wx0 * wy1 * wz0;
    const float w110 = wx0 * wy1 * wz1;
    const float w001 = wx1 * wy0 * wz0;
    const float w101 = wx1 * wy0 * wz1;
    const float w011 = wx1 * wy1 * wz0;
    const float w111 = wx1 * wy1 * wz1;

    float o0 = w000 * t000.x;
    float o1 = w000 * t000.y;
    o0 = fmaf(w100, t100.x, o0);  o1 = fmaf(w100, t100.y, o1);
    o0 = fmaf(w010, t010.x, o0);  o1 = fmaf(w010, t010.y, o1);
    o0 = fmaf(w110, t110.x, o0);  o1 = fmaf(w110, t110.y, o1);
    o0 = fmaf(w001, t001.x, o0);  o1 = fmaf(w001, t001.y, o1);
    o0 = fmaf(w101, t101.x, o0);  o1 = fmaf(w101, t101.y, o1);
    o0 = fmaf(w011, t011.x, o0);  o1 = fmaf(w011, t011.y, o1);
    o0 = fmaf(w111, t111.x, o0);  o1 = fmaf(w111, t111.y, o1);

    ((float2*)out)[tid] = make_float2(o0, o1);
}

extern "C" void kernel_launch(void* const* d_in, const int* in_sizes, int n_in,
                              void* d_out, int out_size, void* d_ws, size_t ws_size,
                              hipStream_t stream) {
    const float* images = (const float*)d_in[0];
    const float* params = (const float*)d_in[1];
    float* out = (float*)d_out;

    const int total_threads = NB * NPTS;          // 8,388,608
    const int blocks = total_threads / 256;       // 32,768
    st3d_kernel<<<blocks, 256, 0, stream>>>(images, params, out);
}

// Round 3
// 170.237 us; speedup vs baseline: 1.4252x; 1.4252x over previous
//
#include <hip/hip_runtime.h>

// SpatialTransformer3D: trilinear resample of (B=4, 128^3, C=2) f32 volume
// through per-batch 3x4 affine.
//
// Round-2 structure: lanes along j (drives x, the memory-contiguous dim) so
// gathers are ~512B contiguous runs per wave; LDS transpose so stores stay
// coalesced along k. Block = 256 thr = 64(j) x 64(k) tile at fixed (b, i).
//
// Reference semantics (verified round 1, absmax 1.6e-2):
//   x_norm = lin(j), y_norm = lin(i), z_norm = lin(k);  lin(t) = -1 + t*2/127
//   x = (sg0+1)*64 etc.; int coords via trunc-toward-zero then clip [0,127]
//   (clip AFTER +1 for the hi tap); weights from CLIPPED int coords.
//   gather idx = z*16384 + y*128 + x, float2 per voxel (both channels).

#define NB 4
#define DIM 128
#define NPTS (DIM * DIM * DIM)

__global__ __launch_bounds__(256) void st3d_kernel(
    const float* __restrict__ images,      // (4, 128,128,128, 2)
    const float* __restrict__ params,      // (4, 12)
    float* __restrict__ out)               // (4, 128,128,128, 2)
{
    // two f32 planes (one per channel), padded to 65 -> conflict-free both phases
    __shared__ float lds0[64][65];
    __shared__ float lds1[64][65];

    const int bt = blockIdx.x;             // 2048 blocks: [b][i][jt][kt]
    const int k0 = (bt & 1) << 6;
    const int j0 = ((bt >> 1) & 1) << 6;
    const int i  = (bt >> 2) & 127;
    const int b  = bt >> 9;

    const int t    = threadIdx.x;
    const int lane = t & 63;
    const int wv   = t >> 6;

    const float* p = params + b * 12;
    const float p0 = p[0], p1 = p[1], p2 = p[2],  p3  = p[3];
    const float p4 = p[4], p5 = p[5], p6 = p[6],  p7  = p[7];
    const float p8 = p[8], p9 = p[9], p10 = p[10], p11 = p[11];

    const float step = 2.0f / 127.0f;
    const int   j  = j0 + lane;
    const float xn = fmaf((float)j, step, -1.0f);
    const float yn = fmaf((float)i, step, -1.0f);

    // k-independent partial sums (tiny rounding diff vs ref is harmless:
    // trilinear output is continuous in the coords; data Lipschitz ~O(1))
    const float bx = p0 * xn + p1 * yn + p3;
    const float by = p4 * xn + p5 * yn + p7;
    const float bz = p8 * xn + p9 * yn + p11;

    const float2* __restrict__ vol = (const float2*)images + (size_t)b * NPTS;

    // ---- phase 1: gather + blend, lanes along j; each wave does 16 k-rows ----
    #pragma unroll 4
    for (int it = 0; it < 16; ++it) {
        const int   kl = (wv << 4) + it;
        const float zn = fmaf((float)(k0 + kl), step, -1.0f);

        const float x = (fmaf(p2,  zn, bx) + 1.0f) * 64.0f;
        const float y = (fmaf(p6,  zn, by) + 1.0f) * 64.0f;
        const float z = (fmaf(p10, zn, bz) + 1.0f) * 64.0f;

        const int xi = (int)x, yi = (int)y, zi = (int)z;   // trunc toward zero
        const int x0 = min(max(xi, 0), 127), x1 = min(max(xi + 1, 0), 127);
        const int y0 = min(max(yi, 0), 127), y1 = min(max(yi + 1, 0), 127);
        const int z0 = min(max(zi, 0), 127), z1 = min(max(zi + 1, 0), 127);

        const float wx0 = (float)x1 - x, wx1 = x - (float)x0;
        const float wy0 = (float)y1 - y, wy1 = y - (float)y0;
        const float wz0 = (float)z1 - z, wz1 = z - (float)z0;

        const int r00 = (z0 << 14) + (y0 << 7);
        const int r10 = (z1 << 14) + (y0 << 7);
        const int r01 = (z0 << 14) + (y1 << 7);
        const int r11 = (z1 << 14) + (y1 << 7);

        const float2 t000 = vol[r00 + x0];
        const float2 t100 = vol[r10 + x0];
        const float2 t010 = vol[r01 + x0];
        const float2 t110 = vol[r11 + x0];
        const float2 t001 = vol[r00 + x1];
        const float2 t101 = vol[r10 + x1];
        const float2 t011 = vol[r01 + x1];
        const float2 t111 = vol[r11 + x1];

        const float w000 = wx0 * wy0 * wz0;
        const float w100 = wx0 * wy0 * wz1;
        const float w010 = wx0 * wy1 * wz0;
        const float w110 = wx0 * wy1 * wz1;
        const float w001 = wx1 * wy0 * wz0;
        const float w101 = wx1 * wy0 * wz1;
        const float w011 = wx1 * wy1 * wz0;
        const float w111 = wx1 * wy1 * wz1;

        float o0 = w000 * t000.x;
        float o1 = w000 * t000.y;
        o0 = fmaf(w100, t100.x, o0);  o1 = fmaf(w100, t100.y, o1);
        o0 = fmaf(w010, t010.x, o0);  o1 = fmaf(w010, t010.y, o1);
        o0 = fmaf(w110, t110.x, o0);  o1 = fmaf(w110, t110.y, o1);
        o0 = fmaf(w001, t001.x, o0);  o1 = fmaf(w001, t001.y, o1);
        o0 = fmaf(w101, t101.x, o0);  o1 = fmaf(w101, t101.y, o1);
        o0 = fmaf(w011, t011.x, o0);  o1 = fmaf(w011, t011.y, o1);
        o0 = fmaf(w111, t111.x, o0);  o1 = fmaf(w111, t111.y, o1);

        lds0[lane][kl] = o0;   // banks = (lane*65+kl)%32 = (lane+kl)%32 -> 2-way, free
        lds1[lane][kl] = o1;
    }

    __syncthreads();

    // ---- phase 2: transposed read, coalesced store along k ----
    float2* __restrict__ outv = (float2*)out + (size_t)(b * DIM + i) * (DIM * DIM);

    #pragma unroll 4
    for (int it = 0; it < 16; ++it) {
        const int jl = (wv << 4) + it;
        const float2 v = make_float2(lds0[jl][lane], lds1[jl][lane]);  // consecutive banks, free
        outv[(size_t)(j0 + jl) * DIM + (k0 + lane)] = v;               // 512B contiguous per wave
    }
}

extern "C" void kernel_launch(void* const* d_in, const int* in_sizes, int n_in,
                              void* d_out, int out_size, void* d_ws, size_t ws_size,
                              hipStream_t stream) {
    const float* images = (const float*)d_in[0];
    const float* params = (const float*)d_in[1];
    float* out = (float*)d_out;

    const int blocks = NB * DIM * 2 * 2;   // 2048 blocks of 256 threads
    st3d_kernel<<<blocks, 256, 0, stream>>>(images, params, out);
}

// Round 4
// 156.097 us; speedup vs baseline: 1.5544x; 1.0906x over previous
//
#include <hip/hip_runtime.h>

// SpatialTransformer3D: trilinear resample of (B=4, 128^3, C=2) f32 volume
// through per-batch 3x4 affine.
//
// R4 structure: lanes along j (x = contiguous dim) -> coalesced gathers;
// LDS transpose -> coalesced stores along k. NEW: phase 1 batches 4
// iterations (32 gathers) into explicit static arrays so the compiler keeps
// 32 loads in flight per wave (R3 had VGPR=52 -> only 8 in flight,
// latency-bound at 20% HBM).
//
// Reference semantics (verified: absmax 1.6e-2 vs 1.76e-1 threshold):
//   x_norm = lin(j), y_norm = lin(i), z_norm = lin(k); lin(t) = -1 + t*2/127
//   x = (sg0+1)*64 etc.; trunc-toward-zero then clip [0,127] (clip AFTER +1
//   for hi tap); weights from CLIPPED int coords; idx = z*16384 + y*128 + x.

#define NB 4
#define DIM 128
#define NPTS (DIM * DIM * DIM)

__global__ __launch_bounds__(256) void st3d_kernel(
    const float* __restrict__ images,      // (4, 128,128,128, 2)
    const float* __restrict__ params,      // (4, 12)
    float* __restrict__ out)               // (4, 128,128,128, 2)
{
    __shared__ float lds0[64][65];   // padded: both phases conflict-free
    __shared__ float lds1[64][65];

    const int bt = blockIdx.x;             // 2048 blocks: [b][i][jt][kt]
    const int k0 = (bt & 1) << 6;
    const int j0 = ((bt >> 1) & 1) << 6;
    const int i  = (bt >> 2) & 127;
    const int b  = bt >> 9;

    const int t    = threadIdx.x;
    const int lane = t & 63;
    const int wv   = t >> 6;

    const float* p = params + b * 12;
    const float p0 = p[0], p1 = p[1], p2 = p[2],  p3  = p[3];
    const float p4 = p[4], p5 = p[5], p6 = p[6],  p7  = p[7];
    const float p8 = p[8], p9 = p[9], p10 = p[10], p11 = p[11];

    const float step = 2.0f / 127.0f;
    const int   j  = j0 + lane;
    const float xn = fmaf((float)j, step, -1.0f);
    const float yn = fmaf((float)i, step, -1.0f);

    const float bx = p0 * xn + p1 * yn + p3;
    const float by = p4 * xn + p5 * yn + p7;
    const float bz = p8 * xn + p9 * yn + p11;

    const float2* __restrict__ vol = (const float2*)images + (size_t)b * NPTS;

    // ---- phase 1: 4 groups x 4 iterations; 32 gathers in flight per group ----
    #pragma unroll
    for (int g = 0; g < 4; ++g) {
        int   idx[4][8];
        float wx0a[4], wx1a[4], wy0a[4], wy1a[4], wz0a[4], wz1a[4];

        #pragma unroll
        for (int u = 0; u < 4; ++u) {
            const int   kl = (wv << 4) + (g << 2) + u;
            const float zn = fmaf((float)(k0 + kl), step, -1.0f);

            const float x = (fmaf(p2,  zn, bx) + 1.0f) * 64.0f;
            const float y = (fmaf(p6,  zn, by) + 1.0f) * 64.0f;
            const float z = (fmaf(p10, zn, bz) + 1.0f) * 64.0f;

            const int xi = (int)x, yi = (int)y, zi = (int)z;  // trunc toward zero
            const int x0 = min(max(xi, 0), 127), x1 = min(max(xi + 1, 0), 127);
            const int y0 = min(max(yi, 0), 127), y1 = min(max(yi + 1, 0), 127);
            const int z0 = min(max(zi, 0), 127), z1 = min(max(zi + 1, 0), 127);

            wx0a[u] = (float)x1 - x;  wx1a[u] = x - (float)x0;
            wy0a[u] = (float)y1 - y;  wy1a[u] = y - (float)y0;
            wz0a[u] = (float)z1 - z;  wz1a[u] = z - (float)z0;

            const int r00 = (z0 << 14) + (y0 << 7);
            const int r10 = (z1 << 14) + (y0 << 7);
            const int r01 = (z0 << 14) + (y1 << 7);
            const int r11 = (z1 << 14) + (y1 << 7);

            idx[u][0] = r00 + x0;  idx[u][1] = r10 + x0;
            idx[u][2] = r01 + x0;  idx[u][3] = r11 + x0;
            idx[u][4] = r00 + x1;  idx[u][5] = r10 + x1;
            idx[u][6] = r01 + x1;  idx[u][7] = r11 + x1;
        }

        // issue all 32 loads back-to-back (static indices after unroll)
        float2 tv[4][8];
        #pragma unroll
        for (int u = 0; u < 4; ++u)
            #pragma unroll
            for (int q = 0; q < 8; ++q)
                tv[u][q] = vol[idx[u][q]];

        // blend + LDS write
        #pragma unroll
        for (int u = 0; u < 4; ++u) {
            const float wx0 = wx0a[u], wx1 = wx1a[u];
            const float wy0 = wy0a[u], wy1 = wy1a[u];
            const float wz0 = wz0a[u], wz1 = wz1a[u];

            const float w000 = wx0 * wy0 * wz0;
            const float w100 = wx0 * wy0 * wz1;
            const float w010 = wx0 * wy1 * wz0;
            const float w110 = wx0 * wy1 * wz1;
            const float w001 = wx1 * wy0 * wz0;
            const float w101 = wx1 * wy0 * wz1;
            const float w011 = wx1 * wy1 * wz0;
            const float w111 = wx1 * wy1 * wz1;

            float o0 = w000 * tv[u][0].x;
            float o1 = w000 * tv[u][0].y;
            o0 = fmaf(w100, tv[u][1].x, o0);  o1 = fmaf(w100, tv[u][1].y, o1);
            o0 = fmaf(w010, tv[u][2].x, o0);  o1 = fmaf(w010, tv[u][2].y, o1);
            o0 = fmaf(w110, tv[u][3].x, o0);  o1 = fmaf(w110, tv[u][3].y, o1);
            o0 = fmaf(w001, tv[u][4].x, o0);  o1 = fmaf(w001, tv[u][4].y, o1);
            o0 = fmaf(w101, tv[u][5].x, o0);  o1 = fmaf(w101, tv[u][5].y, o1);
            o0 = fmaf(w011, tv[u][6].x, o0);  o1 = fmaf(w011, tv[u][6].y, o1);
            o0 = fmaf(w111, tv[u][7].x, o0);  o1 = fmaf(w111, tv[u][7].y, o1);

            const int kl = (wv << 4) + (g << 2) + u;
            lds0[lane][kl] = o0;   // bank = (lane+kl)%32 -> 2-way, free
            lds1[lane][kl] = o1;
        }
    }

    __syncthreads();

    // ---- phase 2: transposed read, coalesced store along k ----
    float2* __restrict__ outv = (float2*)out + (size_t)(b * DIM + i) * (DIM * DIM);

    #pragma unroll 4
    for (int it = 0; it < 16; ++it) {
        const int jl = (wv << 4) + it;
        const float2 v = make_float2(lds0[jl][lane], lds1[jl][lane]);  // consecutive banks
        outv[(size_t)(j0 + jl) * DIM + (k0 + lane)] = v;               // 512B/wave contiguous
    }
}

extern "C" void kernel_launch(void* const* d_in, const int* in_sizes, int n_in,
                              void* d_out, int out_size, void* d_ws, size_t ws_size,
                              hipStream_t stream) {
    const float* images = (const float*)d_in[0];
    const float* params = (const float*)d_in[1];
    float* out = (float*)d_out;

    const int blocks = NB * DIM * 2 * 2;   // 2048 blocks of 256 threads
    st3d_kernel<<<blocks, 256, 0, stream>>>(images, params, out);
}

// Round 6
// 149.657 us; speedup vs baseline: 1.6212x; 1.0430x over previous
//
#include <hip/hip_runtime.h>

// SpatialTransformer3D: trilinear resample of (B=4, 128^3, C=2) f32 volume
// through per-batch 3x4 affine.
//
// R6 = R5 with the nontemporal-store type fixed (native ext_vector float2;
// HIP's float2 class is rejected by __builtin_nontemporal_store).
//
// R5 structure: lanes along j (x = contiguous dim) -> coalesced gathers; LDS
// transpose -> coalesced stores along k. Tile 64(j) x 32(k), LDS 16.9KB ->
// 8 blocks/CU (32-wave cap; R4 was latency-bound at 25% BW, VGPR=64).
// XCD chunked swizzle (concurrent blocks per XCD span ~4 i-slabs -> ~1.6MB
// working set fits 4MB per-XCD L2) + nontemporal output stores.
//
// Reference semantics (verified: absmax 1.6e-2 vs 1.76e-1 threshold):
//   x_norm = lin(j), y_norm = lin(i), z_norm = lin(k); lin(t) = -1 + t*2/127
//   x = (sg0+1)*64 etc.; trunc-toward-zero then clip [0,127] (clip AFTER +1
//   for hi tap); weights from CLIPPED int coords; idx = z*16384 + y*128 + x.

#define NB 4
#define DIM 128
#define NPTS (DIM * DIM * DIM)

typedef float vfloat2 __attribute__((ext_vector_type(2)));

__global__ __launch_bounds__(256) void st3d_kernel(
    const float* __restrict__ images,      // (4, 128,128,128, 2)
    const float* __restrict__ params,      // (4, 12)
    float* __restrict__ out)               // (4, 128,128,128, 2)
{
    __shared__ float lds0[64][33];   // padded: both phases <=2-way (free)
    __shared__ float lds1[64][33];

    // XCD chunked swizzle: physical ids round-robin XCDs; remap so each XCD
    // owns a contiguous logical range (4096 % 8 == 0 -> bijective).
    const int phys = blockIdx.x;
    const int bt   = (phys & 7) * 512 + (phys >> 3);   // 4096 blocks

    // logical layout: [b(2)][i(7)][jt(1)][kt(2)]
    const int k0 = (bt & 3) << 5;          // 4 k-tiles of 32
    const int j0 = ((bt >> 2) & 1) << 6;   // 2 j-tiles of 64
    const int i  = (bt >> 3) & 127;
    const int b  = bt >> 10;

    const int t    = threadIdx.x;
    const int lane = t & 63;
    const int wv   = t >> 6;

    const float* p = params + b * 12;
    const float p0 = p[0], p1 = p[1], p2 = p[2],  p3  = p[3];
    const float p4 = p[4], p5 = p[5], p6 = p[6],  p7  = p[7];
    const float p8 = p[8], p9 = p[9], p10 = p[10], p11 = p[11];

    const float step = 2.0f / 127.0f;
    const int   j  = j0 + lane;
    const float xn = fmaf((float)j, step, -1.0f);
    const float yn = fmaf((float)i, step, -1.0f);

    const float bx = p0 * xn + p1 * yn + p3;
    const float by = p4 * xn + p5 * yn + p7;
    const float bz = p8 * xn + p9 * yn + p11;

    const float2* __restrict__ vol = (const float2*)images + (size_t)b * NPTS;

    // ---- phase 1: 2 groups x 4 k-rows; 32 gathers batched per group ----
    #pragma unroll
    for (int g = 0; g < 2; ++g) {
        int   idx[4][8];
        float wx0a[4], wx1a[4], wy0a[4], wy1a[4], wz0a[4], wz1a[4];

        #pragma unroll
        for (int u = 0; u < 4; ++u) {
            const int   kl = (wv << 3) + (g << 2) + u;   // 8 k-rows per wave
            const float zn = fmaf((float)(k0 + kl), step, -1.0f);

            const float x = (fmaf(p2,  zn, bx) + 1.0f) * 64.0f;
            const float y = (fmaf(p6,  zn, by) + 1.0f) * 64.0f;
            const float z = (fmaf(p10, zn, bz) + 1.0f) * 64.0f;

            const int xi = (int)x, yi = (int)y, zi = (int)z;  // trunc toward 0
            const int x0 = min(max(xi, 0), 127), x1 = min(max(xi + 1, 0), 127);
            const int y0 = min(max(yi, 0), 127), y1 = min(max(yi + 1, 0), 127);
            const int z0 = min(max(zi, 0), 127), z1 = min(max(zi + 1, 0), 127);

            wx0a[u] = (float)x1 - x;  wx1a[u] = x - (float)x0;
            wy0a[u] = (float)y1 - y;  wy1a[u] = y - (float)y0;
            wz0a[u] = (float)z1 - z;  wz1a[u] = z - (float)z0;

            const int r00 = (z0 << 14) + (y0 << 7);
            const int r10 = (z1 << 14) + (y0 << 7);
            const int r01 = (z0 << 14) + (y1 << 7);
            const int r11 = (z1 << 14) + (y1 << 7);

            idx[u][0] = r00 + x0;  idx[u][1] = r10 + x0;
            idx[u][2] = r01 + x0;  idx[u][3] = r11 + x0;
            idx[u][4] = r00 + x1;  idx[u][5] = r10 + x1;
            idx[u][6] = r01 + x1;  idx[u][7] = r11 + x1;
        }

        float2 tv[4][8];
        #pragma unroll
        for (int u = 0; u < 4; ++u)
            #pragma unroll
            for (int q = 0; q < 8; ++q)
                tv[u][q] = vol[idx[u][q]];

        #pragma unroll
        for (int u = 0; u < 4; ++u) {
            const float wx0 = wx0a[u], wx1 = wx1a[u];
            const float wy0 = wy0a[u], wy1 = wy1a[u];
            const float wz0 = wz0a[u], wz1 = wz1a[u];

            const float w000 = wx0 * wy0 * wz0;
            const float w100 = wx0 * wy0 * wz1;
            const float w010 = wx0 * wy1 * wz0;
            const float w110 = wx0 * wy1 * wz1;
            const float w001 = wx1 * wy0 * wz0;
            const float w101 = wx1 * wy0 * wz1;
            const float w011 = wx1 * wy1 * wz0;
            const float w111 = wx1 * wy1 * wz1;

            float o0 = w000 * tv[u][0].x;
            float o1 = w000 * tv[u][0].y;
            o0 = fmaf(w100, tv[u][1].x, o0);  o1 = fmaf(w100, tv[u][1].y, o1);
            o0 = fmaf(w010, tv[u][2].x, o0);  o1 = fmaf(w010, tv[u][2].y, o1);
            o0 = fmaf(w110, tv[u][3].x, o0);  o1 = fmaf(w110, tv[u][3].y, o1);
            o0 = fmaf(w001, tv[u][4].x, o0);  o1 = fmaf(w001, tv[u][4].y, o1);
            o0 = fmaf(w101, tv[u][5].x, o0);  o1 = fmaf(w101, tv[u][5].y, o1);
            o0 = fmaf(w011, tv[u][6].x, o0);  o1 = fmaf(w011, tv[u][6].y, o1);
            o0 = fmaf(w111, tv[u][7].x, o0);  o1 = fmaf(w111, tv[u][7].y, o1);

            const int kl = (wv << 3) + (g << 2) + u;
            lds0[lane][kl] = o0;   // bank = (lane+kl)%32 -> 2-way, free
            lds1[lane][kl] = o1;
        }
    }

    __syncthreads();

    // ---- phase 2: transposed read, coalesced nontemporal store along k ----
    float* __restrict__ outp = out + (size_t)(b * DIM + i) * (DIM * DIM) * 2;

    #pragma unroll
    for (int it = 0; it < 8; ++it) {
        const int jl = (wv << 4) + (it << 1) + (lane >> 5);  // 2 j-rows per iter
        const int kc = lane & 31;
        vfloat2 v;
        v.x = lds0[jl][kc];   // 2-way, free
        v.y = lds1[jl][kc];
        vfloat2* dst = (vfloat2*)(outp + ((size_t)(j0 + jl) * DIM + (k0 + kc)) * 2);
        __builtin_nontemporal_store(v, dst);
    }
}

extern "C" void kernel_launch(void* const* d_in, const int* in_sizes, int n_in,
                              void* d_out, int out_size, void* d_ws, size_t ws_size,
                              hipStream_t stream) {
    const float* images = (const float*)d_in[0];
    const float* params = (const float*)d_in[1];
    float* out = (float*)d_out;

    const int blocks = NB * DIM * 2 * 4;   // 4096 blocks of 256 threads
    st3d_kernel<<<blocks, 256, 0, stream>>>(images, params, out);
}